// Round 7
// baseline (246.615 us; speedup 1.0000x reference)
//
#include <hip/hip_runtime.h>
#include <math.h>

#define NROWS 16384
#define DDIM  2048
#define EEXP  64
#define RB    64               // rows per block
#define KD    64               // d per LDS chunk
#define NCHUNK (DDIM / KD)     // 32
#define XSTR  68               // x tile row stride (dwords), pad 4 -> conflict-free b128
#define PSTR  66               // epilogue partial row stride

#define XOFF(b) ((b) * 4352)   // two x buffers: [2][64][68] floats

// 32 FMAs: one row's 4 d-values (xv float4) against 8 experts (wl*/wh* per d)
#define ROW_FMA(i, XV)                                                        \
    acc[i][0]=fmaf(XV.x,wl0.x,acc[i][0]); acc[i][1]=fmaf(XV.x,wl0.y,acc[i][1]); \
    acc[i][2]=fmaf(XV.x,wl0.z,acc[i][2]); acc[i][3]=fmaf(XV.x,wl0.w,acc[i][3]); \
    acc[i][4]=fmaf(XV.x,wh0.x,acc[i][4]); acc[i][5]=fmaf(XV.x,wh0.y,acc[i][5]); \
    acc[i][6]=fmaf(XV.x,wh0.z,acc[i][6]); acc[i][7]=fmaf(XV.x,wh0.w,acc[i][7]); \
    acc[i][0]=fmaf(XV.y,wl1.x,acc[i][0]); acc[i][1]=fmaf(XV.y,wl1.y,acc[i][1]); \
    acc[i][2]=fmaf(XV.y,wl1.z,acc[i][2]); acc[i][3]=fmaf(XV.y,wl1.w,acc[i][3]); \
    acc[i][4]=fmaf(XV.y,wh1.x,acc[i][4]); acc[i][5]=fmaf(XV.y,wh1.y,acc[i][5]); \
    acc[i][6]=fmaf(XV.y,wh1.z,acc[i][6]); acc[i][7]=fmaf(XV.y,wh1.w,acc[i][7]); \
    acc[i][0]=fmaf(XV.z,wl2.x,acc[i][0]); acc[i][1]=fmaf(XV.z,wl2.y,acc[i][1]); \
    acc[i][2]=fmaf(XV.z,wl2.z,acc[i][2]); acc[i][3]=fmaf(XV.z,wl2.w,acc[i][3]); \
    acc[i][4]=fmaf(XV.z,wh2.x,acc[i][4]); acc[i][5]=fmaf(XV.z,wh2.y,acc[i][5]); \
    acc[i][6]=fmaf(XV.z,wh2.z,acc[i][6]); acc[i][7]=fmaf(XV.z,wh2.w,acc[i][7]); \
    acc[i][0]=fmaf(XV.w,wl3.x,acc[i][0]); acc[i][1]=fmaf(XV.w,wl3.y,acc[i][1]); \
    acc[i][2]=fmaf(XV.w,wl3.z,acc[i][2]); acc[i][3]=fmaf(XV.w,wl3.w,acc[i][3]); \
    acc[i][4]=fmaf(XV.w,wh3.x,acc[i][4]); acc[i][5]=fmaf(XV.w,wh3.y,acc[i][5]); \
    acc[i][6]=fmaf(XV.w,wh3.z,acc[i][6]); acc[i][7]=fmaf(XV.w,wh3.w,acc[i][7]);

// one 4-d group: x from LDS (8 rows b128), w from registers (global-loaded)
#define GROUPW(D0, A0,B0,A1,B1,A2,B2,A3,B3)                                   \
    {                                                                         \
        float4 wl0=A0, wh0=B0, wl1=A1, wh1=B1;                                \
        float4 wl2=A2, wh2=B2, wl3=A3, wh3=B3;                                \
        float4 xv0 = *(const float4*)(xb + 0*544 + (D0));                     \
        float4 xv1 = *(const float4*)(xb + 1*544 + (D0));                     \
        float4 xv2 = *(const float4*)(xb + 2*544 + (D0));                     \
        float4 xv3 = *(const float4*)(xb + 3*544 + (D0));                     \
        float4 xv4 = *(const float4*)(xb + 4*544 + (D0));                     \
        float4 xv5 = *(const float4*)(xb + 5*544 + (D0));                     \
        float4 xv6 = *(const float4*)(xb + 6*544 + (D0));                     \
        float4 xv7 = *(const float4*)(xb + 7*544 + (D0));                     \
        ROW_FMA(0, xv0) ROW_FMA(1, xv1) ROW_FMA(2, xv2) ROW_FMA(3, xv3)       \
        ROW_FMA(4, xv4) ROW_FMA(5, xv5) ROW_FMA(6, xv6) ROW_FMA(7, xv7)       \
    }

__global__ __launch_bounds__(512, 2)
void router_kernel(const float* __restrict__ x,
                   const float* __restrict__ W,
                   const float* __restrict__ bias_v,
                   float* __restrict__ mask_out,
                   float* __restrict__ idx_out) {
    __shared__ __align__(16) float smem[16896];   // x bufs (8704) + epilogue reuse

    const int tid  = threadIdx.x;
    const int lane = tid & 63;
    const int wave = __builtin_amdgcn_readfirstlane(tid >> 6);
    const int eg   = lane & 7;     // experts 8*eg..8*eg+7
    const int rg   = lane >> 3;    // rows rg, rg+8, ..., rg+56
    const int row0 = blockIdx.x * RB;
    const int dw   = wave * 8;     // wave's d-slice within each chunk

    float acc[8][8];
#pragma unroll
    for (int i = 0; i < 8; ++i)
#pragma unroll
        for (int e = 0; e < 8; ++e) acc[i][e] = 0.0f;

    // x staging coords: thread stages 2 float4 per chunk (64 rows x 16 quads)
    const int f0 = tid, f1 = tid + 512;
    const int xr0 = f0 >> 4, xd0 = (f0 & 15) * 4;
    const int xr1 = f1 >> 4, xd1 = (f1 & 15) * 4;
    const float* xsrc0 = x + (size_t)(row0 + xr0) * DDIM + xd0;
    const float* xsrc1 = x + (size_t)(row0 + xr1) * DDIM + xd1;

    // prologue: stage chunk 0 into buf 0
    {
        float4 a = *(const float4*)xsrc0;
        float4 b = *(const float4*)xsrc1;
        *(float4*)(smem + XOFF(0) + xr0 * XSTR + xd0) = a;
        *(float4*)(smem + XOFF(0) + xr1 * XSTR + xd1) = b;
    }

    // w base: float4 index = d*16 + 2*eg, d = c*64 + dw + k
    const float4* wbase = (const float4*)W + (size_t)dw * 16 + 2 * eg;

#pragma unroll 1
    for (int c = 0; c < NCHUNK; ++c) {
        __syncthreads();   // buf[c&1] staged; everyone done reading buf[(c+1)&1]

        // W loads for THIS chunk first (L1/L2-hit; consumed below, vmcnt uncoupled from x)
        const float4* wc4 = wbase + (size_t)c * 1024;
        float4 w0 = wc4[0],   w1 = wc4[1];
        float4 w2 = wc4[16],  w3 = wc4[17];
        float4 w4 = wc4[32],  w5 = wc4[33];
        float4 w6 = wc4[48],  w7 = wc4[49];
        float4 w8 = wc4[64],  w9 = wc4[65];
        float4 wA = wc4[80],  wB = wc4[81];
        float4 wC = wc4[96],  wD = wc4[97];
        float4 wE = wc4[112], wF = wc4[113];

        // x prefetch for chunk c+1 (issued AFTER w -> in-order vmcnt never blocks w)
        const bool more = (c + 1) < NCHUNK;
        float4 px0, px1;
        if (more) {
            px0 = *(const float4*)(xsrc0 + (size_t)(c + 1) * KD);
            px1 = *(const float4*)(xsrc1 + (size_t)(c + 1) * KD);
        }

        const float* xb = smem + XOFF(c & 1) + rg * XSTR;
        GROUPW(dw,     w0, w1, w2, w3, w4, w5, w6, w7)
        GROUPW(dw + 4, w8, w9, wA, wB, wC, wD, wE, wF)

        if (more) {
            const int nb = (c + 1) & 1;
            *(float4*)(smem + XOFF(nb) + xr0 * XSTR + xd0) = px0;
            *(float4*)(smem + XOFF(nb) + xr1 * XSTR + xd1) = px1;
        }
    }

    // ---- epilogue: cross-wave reduction in two 32-row halves (smem reused) ----
    const float bias = bias_v[lane];
#pragma unroll
    for (int h = 0; h < 2; ++h) {
        __syncthreads();   // h=0: compute done; h=1: previous half's reads done
#pragma unroll
        for (int ii = 0; ii < 4; ++ii) {
            const int i  = 4 * h + ii;
            const int rp = rg + 8 * i - 32 * h;     // 0..31
            float* pb = smem + wave * 2112 + rp * PSTR + eg * 8;
            *(float2*)(pb + 0) = make_float2(acc[i][0], acc[i][1]);
            *(float2*)(pb + 2) = make_float2(acc[i][2], acc[i][3]);
            *(float2*)(pb + 4) = make_float2(acc[i][4], acc[i][5]);
            *(float2*)(pb + 6) = make_float2(acc[i][6], acc[i][7]);
        }
        __syncthreads();
#pragma unroll
        for (int rr = 0; rr < 4; ++rr) {
            const int rp  = wave * 4 + rr;
            const int row = row0 + 32 * h + rp;
            float logit = bias;
#pragma unroll
            for (int p = 0; p < 8; ++p) logit += smem[p * 2112 + rp * PSTR + lane];

            float m = logit;
#pragma unroll
            for (int off = 32; off >= 1; off >>= 1)
                m = fmaxf(m, __shfl_xor(m, off));
            float ex = __expf(logit - m);
            float s = ex;
#pragma unroll
            for (int off = 32; off >= 1; off >>= 1)
                s += __shfl_xor(s, off);
            float gate = ex / s;

            float v1 = logit; int i1 = lane;
#pragma unroll
            for (int off = 32; off >= 1; off >>= 1) {
                float ov = __shfl_xor(v1, off);
                int   oi = __shfl_xor(i1, off);
                if (ov > v1 || (ov == v1 && oi < i1)) { v1 = ov; i1 = oi; }
            }
            float v2 = (lane == i1) ? -INFINITY : logit; int i2 = lane;
#pragma unroll
            for (int off = 32; off >= 1; off >>= 1) {
                float ov = __shfl_xor(v2, off);
                int   oi = __shfl_xor(i2, off);
                if (ov > v2 || (ov == v2 && oi < i2)) { v2 = ov; i2 = oi; }
            }

            float outv = (lane == i1 || lane == i2) ? gate : 0.0f;
            mask_out[(size_t)row * EEXP + lane] = outv;
            if (lane == 0) {
                idx_out[row * 2 + 0] = (float)i1;
                idx_out[row * 2 + 1] = (float)i2;
            }
        }
    }
}

extern "C" void kernel_launch(void* const* d_in, const int* in_sizes, int n_in,
                              void* d_out, int out_size, void* d_ws, size_t ws_size,
                              hipStream_t stream) {
    const float* x = (const float*)d_in[0];
    const float* W = (const float*)d_in[1];
    const float* b = (const float*)d_in[2];
    float* mask_out = (float*)d_out;
    float* idx_out  = mask_out + (size_t)NROWS * EEXP;

    dim3 grid(NROWS / RB);   // 256 blocks -> 1 block/CU, 8 waves/CU
    dim3 block(512);
    router_kernel<<<grid, block, 0, stream>>>(x, W, b, mask_out, idx_out);
}